// Round 5
// baseline (480.337 us; speedup 1.0000x reference)
//
#include <hip/hip_runtime.h>
#include <stdint.h>

typedef unsigned long long u64;

#define M_DIM 16384
#define N_DIM 2048
#define K_DIM 2048

// ---------------- i8 MFMA path ----------------
#define BM 256
#define BN 256
#define BK 64
#define NSTAGE (K_DIM / BK)        // 32

typedef int v4i  __attribute__((ext_vector_type(4)));
typedef int v16i __attribute__((ext_vector_type(16)));

// Packed layout (atom = 16 B = 16 k-values of one row, lane l = kh*32+row):
//   A: [m_blk:64][s:32][c:2][t:8][lane:64] atoms   (16 KB per (m_blk,s))
//   B: [n_blk:8][s:32][c:2][t:8][lane:64] atoms    (16 KB per (n_blk,s))
// Every fragment is a lane-linear 1 KB region (base + lane*16): coalesced
// global loads, conflict-free ds_reads (verified R2/R3: 0 conflicts).
// k-permutation inside fragments cancels (A, B packed identically).
//
// R5 design: 4x4 wave tile (128x128/wave, 0.5 KB LDS-read per MFMA vs R3's
// 0.75), 1 wave/SIMD (acc=256 VGPRs), NO __syncthreads anywhere: each wave
// DMAs its own A into a private 2x8KB LDS slice (own-vmcnt), B goes direct
// to VGPRs with a full-stage register double buffer. All consumers trail
// their producers by >= one 32-MFMA compute phase (~1170 cyc).

__device__ __forceinline__ void gld16(void* lds_base, const void* gsrc) {
    __builtin_amdgcn_global_load_lds(
        (const __attribute__((address_space(1))) uint32_t*)gsrc,
        (__attribute__((address_space(3))) uint32_t*)lds_base,
        16, 0, 0);
}

__device__ __forceinline__ int pk4(float a, float b, float c, float d) {
    int r = (a < 0.0f ? 0xFF : 0x01);
    r |= (b < 0.0f ? 0xFF : 0x01) << 8;
    r |= (c < 0.0f ? 0xFF : 0x01) << 16;
    r |= (d < 0.0f ? 0xFF : 0x01) << 24;
    return r;
}

// One wave packs one (row-group of T*32 rows, k-stage): 2*T regions of 1 KB.
template <int T>
__global__ __launch_bounds__(256) void pack_i8_kernel(
        const float* __restrict__ src, char* __restrict__ dst) {
    const int wave_id = (blockIdx.x * 256 + threadIdx.x) >> 6;
    const int lane = threadIdx.x & 63;
    const int s  = wave_id & (NSTAGE - 1);
    const int rg = wave_id >> 5;                  // NSTAGE == 32
    const int r  = lane & 31;
    const int kh = lane >> 5;
    const int regs = 2 * T;
    char* out = dst + ((size_t)rg * NSTAGE + s) * (regs * 1024) + lane * 16;
#pragma unroll 2
    for (int rr = 0; rr < regs; ++rr) {
        const int c = rr / T, t = rr % T;
        const int row = rg * (T * 32) + t * 32 + r;
        const float* p = src + (size_t)row * K_DIM + s * BK + c * 32 + kh * 16;
        const float4 v0 = ((const float4*)p)[0];
        const float4 v1 = ((const float4*)p)[1];
        const float4 v2 = ((const float4*)p)[2];
        const float4 v3 = ((const float4*)p)[3];
        int4 o;
        o.x = pk4(v0.x, v0.y, v0.z, v0.w);
        o.y = pk4(v1.x, v1.y, v1.z, v1.w);
        o.z = pk4(v2.x, v2.y, v2.z, v2.w);
        o.w = pk4(v3.x, v3.y, v3.z, v3.w);
        *(int4*)(out + rr * 1024) = o;
    }
}

__global__ __launch_bounds__(256, 1) void bgemm_i8_kernel(
        const char* __restrict__ Ap, const char* __restrict__ Bp,
        float* __restrict__ C) {
    // Private per-wave A staging: [wave:4][buf:2][8 KB]. No barriers.
    __shared__ __align__(16) char lds[4][2][8192];

    const int t    = threadIdx.x;
    const int lane = t & 63;
    const int wv   = t >> 6;
    const int hm   = wv >> 1;                     // A half: 0/1
    const int hn   = wv & 1;                      // B half: 0/1

    // Swizzle: XCD x owns m_blks [8x,8x+8); per dispatch-round one n-half.
    // Per-XCD/round working set: A 4 MB (4-way block reuse) + B 2 MB.
    const int id    = blockIdx.x;
    const int xcd   = id & 7;
    const int g     = id >> 3;                    // 0..63
    const int kk    = g & 31;
    const int round = g >> 5;                     // 0..1
    const int m_blk = xcd * 8 + (kk >> 2);        // 0..63
    const int n_blk = round * 4 + (kk & 3);       // 0..7

    const char* aG = Ap + (size_t)m_blk * (NSTAGE * 16384) + lane * 16;
    const char* bG = Bp + (size_t)n_blk * (NSTAGE * 16384) + lane * 16;

    v16i acc[4][4];
#pragma unroll
    for (int i = 0; i < 4; ++i)
#pragma unroll
        for (int j = 0; j < 4; ++j)
#pragma unroll
            for (int q = 0; q < 16; ++q) acc[i][j][q] = 0;

    auto dmaA = [&](int s, int buf) {
        const char* a = aG + (size_t)s * 16384;
#pragma unroll
        for (int r = 0; r < 8; ++r) {
            const int reg = (r >> 2) * 8 + hm * 4 + (r & 3);   // [c][t]
            gld16(&lds[wv][buf][r * 1024], a + reg * 1024);
        }
    };
    auto loadB = [&](int s, v4i bf[2][4]) {
        const char* b = bG + (size_t)s * 16384;
#pragma unroll
        for (int c = 0; c < 2; ++c)
#pragma unroll
            for (int j = 0; j < 4; ++j)
                bf[c][j] = *(const v4i*)(b + (c * 8 + hn * 4 + j) * 1024);
    };
    auto compute = [&](int buf, v4i bf[2][4]) {
#pragma unroll
        for (int c = 0; c < 2; ++c) {
            v4i af[4];
#pragma unroll
            for (int i = 0; i < 4; ++i)
                af[i] = *(const v4i*)(&lds[wv][buf][(c * 4 + i) * 1024] + lane * 16);
#pragma unroll
            for (int i = 0; i < 4; ++i)
#pragma unroll
                for (int j = 0; j < 4; ++j)
                    acc[i][j] = __builtin_amdgcn_mfma_i32_32x32x32_i8(
                        af[i], bf[c][j], acc[i][j], 0, 0, 0);
        }
    };

    v4i bf0[2][4], bf1[2][4];
    dmaA(0, 0); loadB(0, bf0);
    dmaA(1, 1); loadB(1, bf1);
#pragma unroll 1
    for (int s = 0; s < NSTAGE; s += 2) {
        compute(0, bf0);                           // stage s (producers >=1 phase old)
        if (s + 2 < NSTAGE) { dmaA(s + 2, 0); loadB(s + 2, bf0); }
        compute(1, bf1);                           // stage s+1
        if (s + 3 < NSTAGE) { dmaA(s + 3, 1); loadB(s + 3, bf1); }
    }

    // C/D layout (HW-measured, dtype-independent):
    //   col = lane&31, row = (q&3) + 8*(q>>2) + 4*(lane>>5)
    const int col = lane & 31;
    const int rq  = (lane >> 5) * 4;
#pragma unroll
    for (int i = 0; i < 4; ++i) {
#pragma unroll
        for (int j = 0; j < 4; ++j) {
            const int mbase = m_blk * BM + (hm * 4 + i) * 32;
            const int nbase = n_blk * BN + (hn * 4 + j) * 32;
#pragma unroll
            for (int q = 0; q < 16; ++q) {
                const int row = mbase + (q & 3) + 8 * (q >> 2) + rq;
                C[(size_t)row * N_DIM + nbase + col] = (float)acc[i][j][q];
            }
        }
    }
}

// ---------------- fallback: u64 XOR-popcount path (R1, known-good) ----------
#define KC 32
#define KT 16
struct alignas(16) u64x2 { u64 x, y; };

__global__ __launch_bounds__(256) void pack_sign_kernel(
        const float* __restrict__ in, u64* __restrict__ out, int ngroups) {
    int wid  = (blockIdx.x * 256 + threadIdx.x) >> 6;
    int lane = threadIdx.x & 63;
    if (wid >= ngroups) return;
    const float4* p = reinterpret_cast<const float4*>(in) + (size_t)wid * 64 + lane;
    float4 v = *p;
    u64 b0 = __ballot(v.x < 0.0f);
    u64 b1 = __ballot(v.y < 0.0f);
    u64 b2 = __ballot(v.z < 0.0f);
    u64 b3 = __ballot(v.w < 0.0f);
    if (lane == 0) {
        u64* o = out + (size_t)wid * 4;
        o[0] = b0; o[1] = b1; o[2] = b2; o[3] = b3;
    }
}

__global__ __launch_bounds__(256, 2) void bgemm_kernel(
        const u64* __restrict__ A, const u64* __restrict__ B,
        float* __restrict__ C) {
    __shared__ u64 As[KT][128];
    __shared__ u64 Bs[KT][128];
    const int t     = threadIdx.x;
    const int m_blk = blockIdx.y << 7;
    const int n_blk = blockIdx.x << 7;
    const int lane = t & 63;
    const int wave = t >> 6;
    const int tm   = lane >> 3;
    const int tn   = lane & 7;
    const int m0   = ((wave >> 1) << 6) + (tm << 3);
    const int n0   = ((wave & 1) << 6) + (tn << 3);
    unsigned acc[8][8];
#pragma unroll
    for (int i = 0; i < 8; ++i)
#pragma unroll
        for (int j = 0; j < 8; ++j) acc[i][j] = 0u;
    const int sr = t >> 3;
    const int sc = (t << 1) & 15;
    for (int ks = 0; ks < K_DIM / (KT * 64); ++ks) {
        const int cbase = ks * KT;
#pragma unroll
        for (int i = 0; i < 4; ++i) {
            int r = i * 32 + sr;
            u64x2 va = *reinterpret_cast<const u64x2*>(A + (size_t)(m_blk + r) * KC + cbase + sc);
            As[sc][r] = va.x; As[sc + 1][r] = va.y;
            u64x2 vb = *reinterpret_cast<const u64x2*>(B + (size_t)(n_blk + r) * KC + cbase + sc);
            Bs[sc][r] = vb.x; Bs[sc + 1][r] = vb.y;
        }
        __syncthreads();
#pragma unroll 1
        for (int c = 0; c < KT; ++c) {
            u64 a[8], b[8];
#pragma unroll
            for (int i = 0; i < 4; ++i) {
                u64x2 va = *reinterpret_cast<const u64x2*>(&As[c][m0 + 2 * i]);
                a[2 * i] = va.x; a[2 * i + 1] = va.y;
                u64x2 vb = *reinterpret_cast<const u64x2*>(&Bs[c][n0 + 2 * i]);
                b[2 * i] = vb.x; b[2 * i + 1] = vb.y;
            }
#pragma unroll
            for (int i = 0; i < 8; ++i)
#pragma unroll
                for (int j = 0; j < 8; ++j)
                    acc[i][j] += (unsigned)__builtin_popcountll(a[i] ^ b[j]);
        }
        __syncthreads();
    }
#pragma unroll
    for (int i = 0; i < 8; ++i) {
        float* o = C + (size_t)(m_blk + m0 + i) * N_DIM + n_blk + n0;
        float4 v0, v1;
        v0.x = (float)(K_DIM - 2 * (int)acc[i][0]);
        v0.y = (float)(K_DIM - 2 * (int)acc[i][1]);
        v0.z = (float)(K_DIM - 2 * (int)acc[i][2]);
        v0.w = (float)(K_DIM - 2 * (int)acc[i][3]);
        v1.x = (float)(K_DIM - 2 * (int)acc[i][4]);
        v1.y = (float)(K_DIM - 2 * (int)acc[i][5]);
        v1.z = (float)(K_DIM - 2 * (int)acc[i][6]);
        v1.w = (float)(K_DIM - 2 * (int)acc[i][7]);
        *reinterpret_cast<float4*>(o)     = v0;
        *reinterpret_cast<float4*>(o + 4) = v1;
    }
}

extern "C" void kernel_launch(void* const* d_in, const int* in_sizes, int n_in,
                              void* d_out, int out_size, void* d_ws, size_t ws_size,
                              hipStream_t stream) {
    const float* x = (const float*)d_in[0];
    const float* w = (const float*)d_in[1];
    float* out = (float*)d_out;

    const size_t needA = (size_t)M_DIM * K_DIM;          // 32 MiB packed i8 A
    const size_t needB = (size_t)N_DIM * K_DIM;          // 4 MiB packed i8 B
    if (ws_size >= needA + needB) {
        char* Ap = (char*)d_ws;
        char* Bp = Ap + needA;
        // A: 64 row-groups (256 rows) x 32 stages = 2048 waves; B: 8 x 32.
        pack_i8_kernel<8><<<2048 / 4, 256, 0, stream>>>(x, Ap);
        pack_i8_kernel<8><<<256 / 4, 256, 0, stream>>>(w, Bp);
        bgemm_i8_kernel<<<(M_DIM / BM) * (N_DIM / BN), 256, 0, stream>>>(Ap, Bp, out);
    } else {
        u64* xb = (u64*)d_ws;
        u64* wb = xb + (size_t)M_DIM * KC;
        int xgroups = (M_DIM * K_DIM) / 256;
        int wgroups = (N_DIM * K_DIM) / 256;
        pack_sign_kernel<<<xgroups / 4, 256, 0, stream>>>(x, xb, xgroups);
        pack_sign_kernel<<<wgroups / 4, 256, 0, stream>>>(w, wb, wgroups);
        bgemm_kernel<<<dim3(N_DIM / 128, M_DIM / 128), 256, 0, stream>>>(xb, wb, out);
    }
}

// Round 6
// 318.793 us; speedup vs baseline: 1.5067x; 1.5067x over previous
//
#include <hip/hip_runtime.h>
#include <stdint.h>

typedef unsigned long long u64;

#define M_DIM 16384
#define N_DIM 2048
#define K_DIM 2048

// ---------------- i8 MFMA path ----------------
#define BM 256
#define BN 256
#define BK 64
#define NSTAGE (K_DIM / BK)        // 32

typedef int v4i  __attribute__((ext_vector_type(4)));
typedef int v16i __attribute__((ext_vector_type(16)));

// Packed layout (atom = 16 B = 16 k-values of one row, lane l = kh*32+row):
//   A: [m_blk:64][s:32][c:2][t:8][lane:64] atoms   (16 KB per (m_blk,s))
//   B: [n_blk:8][s:32][c:2][t:8][lane:64] atoms    (16 KB per (n_blk,s))
// Every fragment is a lane-linear 1 KB region (base + lane*16): coalesced
// global loads + DMA, conflict-free ds_reads (verified R2/R3: 0 conflicts).
// k-permutation inside fragments cancels (A, B packed identically).
//
// R6 design (from R5 post-mortem): 512-thread block, 1 block/CU, 2 waves/
// SIMD (co-scheduling preserved), wave tile 2x4 (acc = 128 AGPR -- NO spill;
// R5's 4x4/256 spilled 494 MB to scratch). BK=64, single barrier per stage,
// DMA issued one full compute phase (~1170 cyc, 2 waves x 16 MFMA) before
// the barrier drain -> exceeds even HBM-miss latency (~900 cyc) -> drain~0.

__device__ __forceinline__ void gld16(void* lds_base, const void* gsrc) {
    __builtin_amdgcn_global_load_lds(
        (const __attribute__((address_space(1))) uint32_t*)gsrc,
        (__attribute__((address_space(3))) uint32_t*)lds_base,
        16, 0, 0);
}

__device__ __forceinline__ int pk4(float a, float b, float c, float d) {
    int r = (a < 0.0f ? 0xFF : 0x01);
    r |= (b < 0.0f ? 0xFF : 0x01) << 8;
    r |= (c < 0.0f ? 0xFF : 0x01) << 16;
    r |= (d < 0.0f ? 0xFF : 0x01) << 24;
    return r;
}

// One wave packs one (row-group of T*32 rows, k-stage): 2*T regions of 1 KB.
template <int T>
__global__ __launch_bounds__(256) void pack_i8_kernel(
        const float* __restrict__ src, char* __restrict__ dst) {
    const int wave_id = (blockIdx.x * 256 + threadIdx.x) >> 6;
    const int lane = threadIdx.x & 63;
    const int s  = wave_id & (NSTAGE - 1);
    const int rg = wave_id >> 5;                  // NSTAGE == 32
    const int r  = lane & 31;
    const int kh = lane >> 5;
    const int regs = 2 * T;
    char* out = dst + ((size_t)rg * NSTAGE + s) * (regs * 1024) + lane * 16;
#pragma unroll 2
    for (int rr = 0; rr < regs; ++rr) {
        const int c = rr / T, t = rr % T;
        const int row = rg * (T * 32) + t * 32 + r;
        const float* p = src + (size_t)row * K_DIM + s * BK + c * 32 + kh * 16;
        const float4 v0 = ((const float4*)p)[0];
        const float4 v1 = ((const float4*)p)[1];
        const float4 v2 = ((const float4*)p)[2];
        const float4 v3 = ((const float4*)p)[3];
        int4 o;
        o.x = pk4(v0.x, v0.y, v0.z, v0.w);
        o.y = pk4(v1.x, v1.y, v1.z, v1.w);
        o.z = pk4(v2.x, v2.y, v2.z, v2.w);
        o.w = pk4(v3.x, v3.y, v3.z, v3.w);
        *(int4*)(out + rr * 1024) = o;
    }
}

__global__ __launch_bounds__(512, 2) void bgemm_i8_kernel(
        const char* __restrict__ Ap, const char* __restrict__ Bp,
        float* __restrict__ C) {
    // Double-buffered stage: [buf:2][A 16 KB | B 16 KB] = 64 KB.
    __shared__ __align__(16) char lds[2][32 * 1024];

    const int t    = threadIdx.x;
    const int lane = t & 63;
    const int wv   = t >> 6;                      // 0..7
    const int wm   = (wv >> 1) & 3;               // m-pair index: 0..3
    const int wn   = wv & 1;                      // n-quad index: 0..1

    // XCD swizzle (R4-proven: FETCH 135->72 MB): XCD x owns m_blks [8x,8x+8);
    // n advances slowest -> per-XCD working set A 4 MB + B slice.
    const int id    = blockIdx.x;
    const int xcd   = id & 7;
    const int idx   = id >> 3;                    // 0..63
    const int m_blk = xcd * 8 + (idx & 7);        // 0..63
    const int n_blk = idx >> 3;                   // 0..7

    const char* aG = Ap + (size_t)m_blk * (NSTAGE * 16384);
    const char* bG = Bp + (size_t)n_blk * (NSTAGE * 16384);

    v16i acc[2][4];
#pragma unroll
    for (int i = 0; i < 2; ++i)
#pragma unroll
        for (int j = 0; j < 4; ++j)
#pragma unroll
            for (int q = 0; q < 16; ++q) acc[i][j][q] = 0;

    // 32 regions/stage (A:16 then B:16), 8 waves x 4 regions, lane-linear.
    auto dma = [&](int s, int buf) {
        const char* a = aG + (size_t)s * 16384;
        const char* b = bG + (size_t)s * 16384;
#pragma unroll
        for (int r = 0; r < 4; ++r) {
            const int reg = wv * 4 + r;
            const char* g = (reg < 16) ? (a + reg * 1024)
                                       : (b + (reg - 16) * 1024);
            gld16(&lds[buf][reg * 1024], g + lane * 16);
        }
    };

    auto compute = [&](int buf) {
        const char* As = lds[buf];
        const char* Bs = lds[buf] + 16384;
#pragma unroll
        for (int c = 0; c < 2; ++c) {
            v4i af[2], bf[4];
#pragma unroll
            for (int i = 0; i < 2; ++i)
                af[i] = *(const v4i*)(As + (c * 8 + wm * 2 + i) * 1024 + lane * 16);
#pragma unroll
            for (int j = 0; j < 4; ++j)
                bf[j] = *(const v4i*)(Bs + (c * 8 + wn * 4 + j) * 1024 + lane * 16);
#pragma unroll
            for (int i = 0; i < 2; ++i)
#pragma unroll
                for (int j = 0; j < 4; ++j)
                    acc[i][j] = __builtin_amdgcn_mfma_i32_32x32x32_i8(
                        af[i], bf[j], acc[i][j], 0, 0, 0);
        }
    };

    dma(0, 0);
    __syncthreads();                       // prologue drain (once)
#pragma unroll 1
    for (int s = 0; s < NSTAGE; ++s) {
        if (s + 1 < NSTAGE) dma(s + 1, (s + 1) & 1);
        compute(s & 1);                    // ~1170 cyc/SIMD: DMA in flight
        __syncthreads();                   // drain ~0; frees buf s&1
    }

    // C/D layout (HW-measured, dtype-independent):
    //   col = lane&31, row = (q&3) + 8*(q>>2) + 4*(lane>>5)
    const int col = lane & 31;
    const int rq  = (lane >> 5) * 4;
#pragma unroll
    for (int i = 0; i < 2; ++i) {
#pragma unroll
        for (int j = 0; j < 4; ++j) {
            const int mbase = m_blk * BM + (wm * 2 + i) * 32;
            const int nbase = n_blk * BN + (wn * 4 + j) * 32;
#pragma unroll
            for (int q = 0; q < 16; ++q) {
                const int row = mbase + (q & 3) + 8 * (q >> 2) + rq;
                C[(size_t)row * N_DIM + nbase + col] = (float)acc[i][j][q];
            }
        }
    }
}

// ---------------- fallback: u64 XOR-popcount path (R1, known-good) ----------
#define KC 32
#define KT 16
struct alignas(16) u64x2 { u64 x, y; };

__global__ __launch_bounds__(256) void pack_sign_kernel(
        const float* __restrict__ in, u64* __restrict__ out, int ngroups) {
    int wid  = (blockIdx.x * 256 + threadIdx.x) >> 6;
    int lane = threadIdx.x & 63;
    if (wid >= ngroups) return;
    const float4* p = reinterpret_cast<const float4*>(in) + (size_t)wid * 64 + lane;
    float4 v = *p;
    u64 b0 = __ballot(v.x < 0.0f);
    u64 b1 = __ballot(v.y < 0.0f);
    u64 b2 = __ballot(v.z < 0.0f);
    u64 b3 = __ballot(v.w < 0.0f);
    if (lane == 0) {
        u64* o = out + (size_t)wid * 4;
        o[0] = b0; o[1] = b1; o[2] = b2; o[3] = b3;
    }
}

__global__ __launch_bounds__(256, 2) void bgemm_kernel(
        const u64* __restrict__ A, const u64* __restrict__ B,
        float* __restrict__ C) {
    __shared__ u64 As[KT][128];
    __shared__ u64 Bs[KT][128];
    const int t     = threadIdx.x;
    const int m_blk = blockIdx.y << 7;
    const int n_blk = blockIdx.x << 7;
    const int lane = t & 63;
    const int wave = t >> 6;
    const int tm   = lane >> 3;
    const int tn   = lane & 7;
    const int m0   = ((wave >> 1) << 6) + (tm << 3);
    const int n0   = ((wave & 1) << 6) + (tn << 3);
    unsigned acc[8][8];
#pragma unroll
    for (int i = 0; i < 8; ++i)
#pragma unroll
        for (int j = 0; j < 8; ++j) acc[i][j] = 0u;
    const int sr = t >> 3;
    const int sc = (t << 1) & 15;
    for (int ks = 0; ks < K_DIM / (KT * 64); ++ks) {
        const int cbase = ks * KT;
#pragma unroll
        for (int i = 0; i < 4; ++i) {
            int r = i * 32 + sr;
            u64x2 va = *reinterpret_cast<const u64x2*>(A + (size_t)(m_blk + r) * KC + cbase + sc);
            As[sc][r] = va.x; As[sc + 1][r] = va.y;
            u64x2 vb = *reinterpret_cast<const u64x2*>(B + (size_t)(n_blk + r) * KC + cbase + sc);
            Bs[sc][r] = vb.x; Bs[sc + 1][r] = vb.y;
        }
        __syncthreads();
#pragma unroll 1
        for (int c = 0; c < KT; ++c) {
            u64 a[8], b[8];
#pragma unroll
            for (int i = 0; i < 4; ++i) {
                u64x2 va = *reinterpret_cast<const u64x2*>(&As[c][m0 + 2 * i]);
                a[2 * i] = va.x; a[2 * i + 1] = va.y;
                u64x2 vb = *reinterpret_cast<const u64x2*>(&Bs[c][n0 + 2 * i]);
                b[2 * i] = vb.x; b[2 * i + 1] = vb.y;
            }
#pragma unroll
            for (int i = 0; i < 8; ++i)
#pragma unroll
                for (int j = 0; j < 8; ++j)
                    acc[i][j] += (unsigned)__builtin_popcountll(a[i] ^ b[j]);
        }
        __syncthreads();
    }
#pragma unroll
    for (int i = 0; i < 8; ++i) {
        float* o = C + (size_t)(m_blk + m0 + i) * N_DIM + n_blk + n0;
        float4 v0, v1;
        v0.x = (float)(K_DIM - 2 * (int)acc[i][0]);
        v0.y = (float)(K_DIM - 2 * (int)acc[i][1]);
        v0.z = (float)(K_DIM - 2 * (int)acc[i][2]);
        v0.w = (float)(K_DIM - 2 * (int)acc[i][3]);
        v1.x = (float)(K_DIM - 2 * (int)acc[i][4]);
        v1.y = (float)(K_DIM - 2 * (int)acc[i][5]);
        v1.z = (float)(K_DIM - 2 * (int)acc[i][6]);
        v1.w = (float)(K_DIM - 2 * (int)acc[i][7]);
        *reinterpret_cast<float4*>(o)     = v0;
        *reinterpret_cast<float4*>(o + 4) = v1;
    }
}

extern "C" void kernel_launch(void* const* d_in, const int* in_sizes, int n_in,
                              void* d_out, int out_size, void* d_ws, size_t ws_size,
                              hipStream_t stream) {
    const float* x = (const float*)d_in[0];
    const float* w = (const float*)d_in[1];
    float* out = (float*)d_out;

    const size_t needA = (size_t)M_DIM * K_DIM;          // 32 MiB packed i8 A
    const size_t needB = (size_t)N_DIM * K_DIM;          // 4 MiB packed i8 B
    if (ws_size >= needA + needB) {
        char* Ap = (char*)d_ws;
        char* Bp = Ap + needA;
        // A: 64 row-groups (256 rows) x 32 stages = 2048 waves; B: 8 x 32.
        pack_i8_kernel<8><<<2048 / 4, 256, 0, stream>>>(x, Ap);
        pack_i8_kernel<8><<<256 / 4, 256, 0, stream>>>(w, Bp);
        bgemm_i8_kernel<<<(M_DIM / BM) * (N_DIM / BN), 512, 0, stream>>>(Ap, Bp, out);
    } else {
        u64* xb = (u64*)d_ws;
        u64* wb = xb + (size_t)M_DIM * KC;
        int xgroups = (M_DIM * K_DIM) / 256;
        int wgroups = (N_DIM * K_DIM) / 256;
        pack_sign_kernel<<<xgroups / 4, 256, 0, stream>>>(x, xb, xgroups);
        pack_sign_kernel<<<wgroups / 4, 256, 0, stream>>>(w, wb, wgroups);
        bgemm_kernel<<<dim3(N_DIM / 128, M_DIM / 128), 256, 0, stream>>>(xb, wb, out);
    }
}

// Round 7
// 314.406 us; speedup vs baseline: 1.5278x; 1.0140x over previous
//
#include <hip/hip_runtime.h>
#include <stdint.h>

typedef unsigned long long u64;

#define M_DIM 16384
#define N_DIM 2048
#define K_DIM 2048

// ---------------- i8 MFMA path ----------------
#define BM 256
#define BN 256
#define BK 128
#define NST (K_DIM / BK)           // 16 stages
#define PACK_S 32                  // pack-granule stages (64-k each), layout unchanged

typedef int v4i  __attribute__((ext_vector_type(4)));
typedef int v16i __attribute__((ext_vector_type(16)));

// Packed layout (atom = 16 B = 16 k-values of one row, lane l = kh*32+row):
//   A: [m_blk:64][ps:32][c:2][t:8][lane:64] atoms   (16 KB per (m_blk,ps))
//   B: [n_blk:8][ps:32][c:2][t:8][lane:64] atoms
// A BK=128 stage = 2 adjacent 16 KB blobs = 32 KB contiguous; region r in
// [0,32) at byte r*1024, r = sub*16 + c*8 + t. Every region is lane-linear
// (base + lane*16): coalesced DMA, conflict-free ds_reads (R2/R3: 0
// conflicts). k-permutation cancels (A,B packed identically).
//
// R7 hypothesis: the ~1800 cyc/stage invariant (R2/R3/R6 all ~2900-3800
// cyc/slot vs 1170 MFMA floor) is PER-STAGE FIXED (barrier skew + read/MFMA
// phase convoy). BK=128 halves stage count to amortize it; per-wave rotated
// k-chunk order de-convoys read vs MFMA phases across waves.
// acc stays 2x4 = 128 AGPR (R5 lesson: 256-acc spills);
// 512-thr 1 block/CU, 2 waves/SIMD (R5 lesson: never 1 wave/SIMD).

__device__ __forceinline__ void gld16(void* lds_base, const void* gsrc) {
    __builtin_amdgcn_global_load_lds(
        (const __attribute__((address_space(1))) uint32_t*)gsrc,
        (__attribute__((address_space(3))) uint32_t*)lds_base,
        16, 0, 0);
}

__device__ __forceinline__ int pk4(float a, float b, float c, float d) {
    int r = (a < 0.0f ? 0xFF : 0x01);
    r |= (b < 0.0f ? 0xFF : 0x01) << 8;
    r |= (c < 0.0f ? 0xFF : 0x01) << 16;
    r |= (d < 0.0f ? 0xFF : 0x01) << 24;
    return r;
}

// One wave packs one (row-group of T*32 rows, 64-k granule): 2*T regions.
template <int T>
__global__ __launch_bounds__(256) void pack_i8_kernel(
        const float* __restrict__ src, char* __restrict__ dst) {
    const int wave_id = (blockIdx.x * 256 + threadIdx.x) >> 6;
    const int lane = threadIdx.x & 63;
    const int s  = wave_id & (PACK_S - 1);
    const int rg = wave_id >> 5;                  // PACK_S == 32
    const int r  = lane & 31;
    const int kh = lane >> 5;
    const int regs = 2 * T;
    char* out = dst + ((size_t)rg * PACK_S + s) * (regs * 1024) + lane * 16;
#pragma unroll 2
    for (int rr = 0; rr < regs; ++rr) {
        const int c = rr / T, t = rr % T;
        const int row = rg * (T * 32) + t * 32 + r;
        const float* p = src + (size_t)row * K_DIM + s * 64 + c * 32 + kh * 16;
        const float4 v0 = ((const float4*)p)[0];
        const float4 v1 = ((const float4*)p)[1];
        const float4 v2 = ((const float4*)p)[2];
        const float4 v3 = ((const float4*)p)[3];
        int4 o;
        o.x = pk4(v0.x, v0.y, v0.z, v0.w);
        o.y = pk4(v1.x, v1.y, v1.z, v1.w);
        o.z = pk4(v2.x, v2.y, v2.z, v2.w);
        o.w = pk4(v3.x, v3.y, v3.z, v3.w);
        *(int4*)(out + rr * 1024) = o;
    }
}

__global__ __launch_bounds__(512, 2) void bgemm_i8_kernel(
        const char* __restrict__ Ap, const char* __restrict__ Bp,
        float* __restrict__ C) {
    // Double-buffered stage: [buf:2][A 32 KB | B 32 KB] = 128 KB (of 160).
    __shared__ __align__(16) char lds[2][64 * 1024];

    const int t    = threadIdx.x;
    const int lane = t & 63;
    const int wv   = t >> 6;                      // 0..7
    const int wm   = (wv >> 1) & 3;               // m-pair index: 0..3
    const int wn   = wv & 1;                      // n-quad index: 0..1

    // XCD swizzle (R4-proven): XCD x owns m_blks [8x,8x+8).
    const int id    = blockIdx.x;
    const int xcd   = id & 7;
    const int idx   = id >> 3;                    // 0..63
    const int m_blk = xcd * 8 + (idx & 7);        // 0..63
    const int n_blk = idx >> 3;                   // 0..7

    const char* aG = Ap + (size_t)m_blk * (NST * 32768);
    const char* bG = Bp + (size_t)n_blk * (NST * 32768);

    v16i acc[2][4];
#pragma unroll
    for (int i = 0; i < 2; ++i)
#pragma unroll
        for (int j = 0; j < 4; ++j)
#pragma unroll
            for (int q = 0; q < 16; ++q) acc[i][j][q] = 0;

    // 64 regions/stage (A:32 then B:32), 8 waves x 8 regions, lane-linear.
    auto dma = [&](int s, int buf) {
        const char* a = aG + (size_t)s * 32768;
        const char* b = bG + (size_t)s * 32768;
#pragma unroll
        for (int r = 0; r < 8; ++r) {
            const int reg = wv * 8 + r;
            const char* g = (reg < 32) ? (a + reg * 1024)
                                       : (b + (reg - 32) * 1024);
            gld16(&lds[buf][reg * 1024], g + lane * 16);
        }
    };

    // 4 k-chunks per stage; each wave starts at a rotated chunk so read
    // phases and MFMA phases interleave across co-resident waves.
    auto compute = [&](int buf) {
        const char* As = lds[buf];
        const char* Bs = lds[buf] + 32768;
#pragma unroll
        for (int cc = 0; cc < 4; ++cc) {
            const int kk = (cc + wv) & 3;          // chunk = (sub, c)
            const int roff = ((kk >> 1) * 16 + (kk & 1) * 8) * 1024;
            v4i af[2], bf[4];
#pragma unroll
            for (int i = 0; i < 2; ++i)
                af[i] = *(const v4i*)(As + roff + (wm * 2 + i) * 1024 + lane * 16);
#pragma unroll
            for (int j = 0; j < 4; ++j)
                bf[j] = *(const v4i*)(Bs + roff + (wn * 4 + j) * 1024 + lane * 16);
#pragma unroll
            for (int i = 0; i < 2; ++i)
#pragma unroll
                for (int j = 0; j < 4; ++j)
                    acc[i][j] = __builtin_amdgcn_mfma_i32_32x32x32_i8(
                        af[i], bf[j], acc[i][j], 0, 0, 0);
        }
    };

    dma(0, 0);
    __syncthreads();                       // prologue drain (once)
#pragma unroll 1
    for (int s = 0; s < NST; ++s) {
        if (s + 1 < NST) dma(s + 1, (s + 1) & 1);
        compute(s & 1);                    // ~2340 cyc/SIMD: DMA in flight
        __syncthreads();                   // drain ~0; frees buf s&1
    }

    // C/D layout (HW-measured, dtype-independent):
    //   col = lane&31, row = (q&3) + 8*(q>>2) + 4*(lane>>5)
    const int col = lane & 31;
    const int rq  = (lane >> 5) * 4;
#pragma unroll
    for (int i = 0; i < 2; ++i) {
#pragma unroll
        for (int j = 0; j < 4; ++j) {
            const int mbase = m_blk * BM + (wm * 2 + i) * 32;
            const int nbase = n_blk * BN + (wn * 4 + j) * 32;
#pragma unroll
            for (int q = 0; q < 16; ++q) {
                const int row = mbase + (q & 3) + 8 * (q >> 2) + rq;
                C[(size_t)row * N_DIM + nbase + col] = (float)acc[i][j][q];
            }
        }
    }
}

// ---------------- fallback: u64 XOR-popcount path (R1, known-good) ----------
#define KC 32
#define KT 16
struct alignas(16) u64x2 { u64 x, y; };

__global__ __launch_bounds__(256) void pack_sign_kernel(
        const float* __restrict__ in, u64* __restrict__ out, int ngroups) {
    int wid  = (blockIdx.x * 256 + threadIdx.x) >> 6;
    int lane = threadIdx.x & 63;
    if (wid >= ngroups) return;
    const float4* p = reinterpret_cast<const float4*>(in) + (size_t)wid * 64 + lane;
    float4 v = *p;
    u64 b0 = __ballot(v.x < 0.0f);
    u64 b1 = __ballot(v.y < 0.0f);
    u64 b2 = __ballot(v.z < 0.0f);
    u64 b3 = __ballot(v.w < 0.0f);
    if (lane == 0) {
        u64* o = out + (size_t)wid * 4;
        o[0] = b0; o[1] = b1; o[2] = b2; o[3] = b3;
    }
}

__global__ __launch_bounds__(256, 2) void bgemm_kernel(
        const u64* __restrict__ A, const u64* __restrict__ B,
        float* __restrict__ C) {
    __shared__ u64 As[KT][128];
    __shared__ u64 Bs[KT][128];
    const int t     = threadIdx.x;
    const int m_blk = blockIdx.y << 7;
    const int n_blk = blockIdx.x << 7;
    const int lane = t & 63;
    const int wave = t >> 6;
    const int tm   = lane >> 3;
    const int tn   = lane & 7;
    const int m0   = ((wave >> 1) << 6) + (tm << 3);
    const int n0   = ((wave & 1) << 6) + (tn << 3);
    unsigned acc[8][8];
#pragma unroll
    for (int i = 0; i < 8; ++i)
#pragma unroll
        for (int j = 0; j < 8; ++j) acc[i][j] = 0u;
    const int sr = t >> 3;
    const int sc = (t << 1) & 15;
    for (int ks = 0; ks < K_DIM / (KT * 64); ++ks) {
        const int cbase = ks * KT;
#pragma unroll
        for (int i = 0; i < 4; ++i) {
            int r = i * 32 + sr;
            u64x2 va = *reinterpret_cast<const u64x2*>(A + (size_t)(m_blk + r) * KC + cbase + sc);
            As[sc][r] = va.x; As[sc + 1][r] = va.y;
            u64x2 vb = *reinterpret_cast<const u64x2*>(B + (size_t)(n_blk + r) * KC + cbase + sc);
            Bs[sc][r] = vb.x; Bs[sc + 1][r] = vb.y;
        }
        __syncthreads();
#pragma unroll 1
        for (int c = 0; c < KT; ++c) {
            u64 a[8], b[8];
#pragma unroll
            for (int i = 0; i < 4; ++i) {
                u64x2 va = *reinterpret_cast<const u64x2*>(&As[c][m0 + 2 * i]);
                a[2 * i] = va.x; a[2 * i + 1] = va.y;
                u64x2 vb = *reinterpret_cast<const u64x2*>(&Bs[c][n0 + 2 * i]);
                b[2 * i] = vb.x; b[2 * i + 1] = vb.y;
            }
#pragma unroll
            for (int i = 0; i < 8; ++i)
#pragma unroll
                for (int j = 0; j < 8; ++j)
                    acc[i][j] += (unsigned)__builtin_popcountll(a[i] ^ b[j]);
        }
        __syncthreads();
    }
#pragma unroll
    for (int i = 0; i < 8; ++i) {
        float* o = C + (size_t)(m_blk + m0 + i) * N_DIM + n_blk + n0;
        float4 v0, v1;
        v0.x = (float)(K_DIM - 2 * (int)acc[i][0]);
        v0.y = (float)(K_DIM - 2 * (int)acc[i][1]);
        v0.z = (float)(K_DIM - 2 * (int)acc[i][2]);
        v0.w = (float)(K_DIM - 2 * (int)acc[i][3]);
        v1.x = (float)(K_DIM - 2 * (int)acc[i][4]);
        v1.y = (float)(K_DIM - 2 * (int)acc[i][5]);
        v1.z = (float)(K_DIM - 2 * (int)acc[i][6]);
        v1.w = (float)(K_DIM - 2 * (int)acc[i][7]);
        *reinterpret_cast<float4*>(o)     = v0;
        *reinterpret_cast<float4*>(o + 4) = v1;
    }
}

extern "C" void kernel_launch(void* const* d_in, const int* in_sizes, int n_in,
                              void* d_out, int out_size, void* d_ws, size_t ws_size,
                              hipStream_t stream) {
    const float* x = (const float*)d_in[0];
    const float* w = (const float*)d_in[1];
    float* out = (float*)d_out;

    const size_t needA = (size_t)M_DIM * K_DIM;          // 32 MiB packed i8 A
    const size_t needB = (size_t)N_DIM * K_DIM;          // 4 MiB packed i8 B
    if (ws_size >= needA + needB) {
        char* Ap = (char*)d_ws;
        char* Bp = Ap + needA;
        // A: 64 row-groups (256 rows) x 32 granules = 2048 waves; B: 8 x 32.
        pack_i8_kernel<8><<<2048 / 4, 256, 0, stream>>>(x, Ap);
        pack_i8_kernel<8><<<256 / 4, 256, 0, stream>>>(w, Bp);
        bgemm_i8_kernel<<<(M_DIM / BM) * (N_DIM / BN), 512, 0, stream>>>(Ap, Bp, out);
    } else {
        u64* xb = (u64*)d_ws;
        u64* wb = xb + (size_t)M_DIM * KC;
        int xgroups = (M_DIM * K_DIM) / 256;
        int wgroups = (N_DIM * K_DIM) / 256;
        pack_sign_kernel<<<xgroups / 4, 256, 0, stream>>>(x, xb, xgroups);
        pack_sign_kernel<<<wgroups / 4, 256, 0, stream>>>(w, wb, wgroups);
        bgemm_kernel<<<dim3(N_DIM / 128, M_DIM / 128), 256, 0, stream>>>(xb, wb, out);
    }
}

// Round 8
// 286.328 us; speedup vs baseline: 1.6776x; 1.0981x over previous
//
#include <hip/hip_runtime.h>
#include <stdint.h>

typedef unsigned long long u64;

#define M_DIM 16384
#define N_DIM 2048
#define K_DIM 2048

// ---------------- fp4 MX-MFMA path ----------------
// C = x @ sign(w)^T with both operands in {-1,+1}: representable EXACTLY in
// fp4 e2m1 (+1 = 0x2, -1 = 0xA). mfma_scale_f32_32x32x64_f8f6f4 with
// scale = E8M0 0x7F (=1.0) computes exact +-1 products, f32 accumulation of
// integer partial sums |.| <= 2048 is exact -> absmax must be 0.
//
// R8 rationale (R7 discriminator): per-stage cost is PER-BYTE (LDS pipe at
// its ~85-90 B/cyc b128 ceiling: 256 KB/stage / 2900 cyc observed invariant
// R2/R3/R6/R7). fp4 halves bytes per element AND doubles MFMA rate
// (9099 vs 4404 TOPS): stage -> ~1550 cyc. Structure = R6 (512 thr,
// 1 block/CU, 2 waves/SIMD, acc 2x4 = 128 regs, single barrier/stage).

#define BM 256
#define BN 256
#define BK 128
#define NST (K_DIM / BK)           // 16 stages
// Region = 1 KB = one 32(m/n) x 64(k) fp4 fragment tile; lane l holds
// row = l&31, k-half = l>>5, 32 nibbles (16 B) at region + l*16.
// A: [m_blk:64][stage:16][sub:2][t:8] regions (16 KB/stage, 256 KB/m_blk)
// B: [n_blk:8][stage:16][sub:2][t:8] regions
// All regions lane-linear -> coalesced DMA + conflict-free ds_read_b128.
// k/nibble permutations cancel (A,B packed identically; HW A/B maps
// symmetric). Total packed: A 16 MB + B 2 MB.

typedef int   v4i  __attribute__((ext_vector_type(4)));
typedef int   v8i  __attribute__((ext_vector_type(8)));
typedef float v16f __attribute__((ext_vector_type(16)));

__device__ __forceinline__ void gld16(void* lds_base, const void* gsrc) {
    __builtin_amdgcn_global_load_lds(
        (const __attribute__((address_space(1))) uint32_t*)gsrc,
        (__attribute__((address_space(3))) uint32_t*)lds_base,
        16, 0, 0);
}

// Pack 8 floats -> 8 fp4 nibbles (one int). e2m1: +1=0x2, -1=0xA.
__device__ __forceinline__ int pkn(float4 a, float4 b) {
    int r;
    r  = (a.x < 0.0f ? 0xA : 0x2);
    r |= (a.y < 0.0f ? 0xA : 0x2) << 4;
    r |= (a.z < 0.0f ? 0xA : 0x2) << 8;
    r |= (a.w < 0.0f ? 0xA : 0x2) << 12;
    r |= (b.x < 0.0f ? 0xA : 0x2) << 16;
    r |= (b.y < 0.0f ? 0xA : 0x2) << 20;
    r |= (b.z < 0.0f ? 0xA : 0x2) << 24;
    r |= (b.w < 0.0f ? 0xA : 0x2) << 28;
    return r;
}

// One wave packs one region: wave_id = ((blk*16 + stage)*2 + sub)*8 + t.
// Lane reads 32 consecutive floats of its row, writes 16 B.
__global__ __launch_bounds__(256) void pack_fp4_kernel(
        const float* __restrict__ src, char* __restrict__ dst) {
    const int wid  = (blockIdx.x * 256 + threadIdx.x) >> 6;
    const int lane = threadIdx.x & 63;
    const int t    = wid & 7;
    const int sub  = (wid >> 3) & 1;
    const int st   = (wid >> 4) & 15;
    const int blk  = wid >> 8;
    const int row  = blk * 256 + t * 32 + (lane & 31);
    const int kb   = st * 128 + sub * 64 + (lane >> 5) * 32;
    const float4* p = (const float4*)(src + (size_t)row * K_DIM + kb);
    int4 o;
    o.x = pkn(p[0], p[1]);
    o.y = pkn(p[2], p[3]);
    o.z = pkn(p[4], p[5]);
    o.w = pkn(p[6], p[7]);
    *(int4*)(dst + (size_t)wid * 1024 + lane * 16) = o;
}

__device__ __forceinline__ v8i up8(v4i v) {
    // fp4 operand data lives in the low 4 of the 8 operand VGPRs.
    v8i r;
    r[0] = v[0]; r[1] = v[1]; r[2] = v[2]; r[3] = v[3];
    r[4] = 0;    r[5] = 0;    r[6] = 0;    r[7] = 0;
    return r;
}

__global__ __launch_bounds__(512, 2) void bgemm_fp4_kernel(
        const char* __restrict__ Ap, const char* __restrict__ Bp,
        float* __restrict__ C) {
    // Double-buffered stage: [buf:2][A 16 KB | B 16 KB] = 64 KB.
    __shared__ __align__(16) char lds[2][32 * 1024];

    const int t    = threadIdx.x;
    const int lane = t & 63;
    const int wv   = t >> 6;                      // 0..7
    const int wm   = (wv >> 1) & 3;               // m-pair: 0..3
    const int wn   = wv & 1;                      // n-quad: 0..1

    // XCD swizzle (R4-proven): XCD x owns m_blks [8x,8x+8).
    const int id    = blockIdx.x;
    const int xcd   = id & 7;
    const int idx   = id >> 3;                    // 0..63
    const int m_blk = xcd * 8 + (idx & 7);        // 0..63
    const int n_blk = idx >> 3;                   // 0..7

    const char* aG = Ap + (size_t)m_blk * (NST * 16384);
    const char* bG = Bp + (size_t)n_blk * (NST * 16384);

    v16f acc[2][4];
#pragma unroll
    for (int i = 0; i < 2; ++i)
#pragma unroll
        for (int j = 0; j < 4; ++j)
#pragma unroll
            for (int q = 0; q < 16; ++q) acc[i][j][q] = 0.0f;

    // 32 regions/stage (A:16 then B:16), 8 waves x 4 regions, lane-linear.
    auto dma = [&](int s, int buf) {
        const char* a = aG + (size_t)s * 16384;
        const char* b = bG + (size_t)s * 16384;
#pragma unroll
        for (int r = 0; r < 4; ++r) {
            const int reg = wv * 4 + r;
            const char* g = (reg < 16) ? (a + reg * 1024)
                                       : (b + (reg - 16) * 1024);
            gld16(&lds[buf][reg * 1024], g + lane * 16);
        }
    };

    auto compute = [&](int buf) {
        const char* As = lds[buf];
        const char* Bs = lds[buf] + 16384;
#pragma unroll
        for (int sub = 0; sub < 2; ++sub) {
            v8i af[2], bf[4];
#pragma unroll
            for (int i = 0; i < 2; ++i)
                af[i] = up8(*(const v4i*)(As + (sub * 8 + wm * 2 + i) * 1024 + lane * 16));
#pragma unroll
            for (int j = 0; j < 4; ++j)
                bf[j] = up8(*(const v4i*)(Bs + (sub * 8 + wn * 4 + j) * 1024 + lane * 16));
#pragma unroll
            for (int i = 0; i < 2; ++i)
#pragma unroll
                for (int j = 0; j < 4; ++j)
                    acc[i][j] = __builtin_amdgcn_mfma_scale_f32_32x32x64_f8f6f4(
                        af[i], bf[j], acc[i][j],
                        4, 4,                     // cbsz=fp4, blgp=fp4
                        0, 0x7F7F7F7F,            // A scale = 1.0 (E8M0 127)
                        0, 0x7F7F7F7F);           // B scale = 1.0
        }
    };

    dma(0, 0);
    __syncthreads();                       // prologue drain (once)
#pragma unroll 1
    for (int s = 0; s < NST; ++s) {
        if (s + 1 < NST) dma(s + 1, (s + 1) & 1);
        compute(s & 1);                    // ~1100+ cyc/SIMD, DMA in flight
        __syncthreads();
    }

    // C/D layout (HW-measured, shape-determined -- m127/m128 incl. f8f6f4):
    //   col = lane&31, row = (q&3) + 8*(q>>2) + 4*(lane>>5)
    const int col = lane & 31;
    const int rq  = (lane >> 5) * 4;
#pragma unroll
    for (int i = 0; i < 2; ++i) {
#pragma unroll
        for (int j = 0; j < 4; ++j) {
            const int mbase = m_blk * BM + (wm * 2 + i) * 32;
            const int nbase = n_blk * BN + (wn * 4 + j) * 32;
#pragma unroll
            for (int q = 0; q < 16; ++q) {
                const int row = mbase + (q & 3) + 8 * (q >> 2) + rq;
                C[(size_t)row * N_DIM + nbase + col] = acc[i][j][q];
            }
        }
    }
}

// ---------------- fallback: u64 XOR-popcount path (R1, known-good) ----------
#define KC 32
#define KT 16
struct alignas(16) u64x2 { u64 x, y; };

__global__ __launch_bounds__(256) void pack_sign_kernel(
        const float* __restrict__ in, u64* __restrict__ out, int ngroups) {
    int wid  = (blockIdx.x * 256 + threadIdx.x) >> 6;
    int lane = threadIdx.x & 63;
    if (wid >= ngroups) return;
    const float4* p = reinterpret_cast<const float4*>(in) + (size_t)wid * 64 + lane;
    float4 v = *p;
    u64 b0 = __ballot(v.x < 0.0f);
    u64 b1 = __ballot(v.y < 0.0f);
    u64 b2 = __ballot(v.z < 0.0f);
    u64 b3 = __ballot(v.w < 0.0f);
    if (lane == 0) {
        u64* o = out + (size_t)wid * 4;
        o[0] = b0; o[1] = b1; o[2] = b2; o[3] = b3;
    }
}

__global__ __launch_bounds__(256, 2) void bgemm_kernel(
        const u64* __restrict__ A, const u64* __restrict__ B,
        float* __restrict__ C) {
    __shared__ u64 As[KT][128];
    __shared__ u64 Bs[KT][128];
    const int t     = threadIdx.x;
    const int m_blk = blockIdx.y << 7;
    const int n_blk = blockIdx.x << 7;
    const int lane = t & 63;
    const int wave = t >> 6;
    const int tm   = lane >> 3;
    const int tn   = lane & 7;
    const int m0   = ((wave >> 1) << 6) + (tm << 3);
    const int n0   = ((wave & 1) << 6) + (tn << 3);
    unsigned acc[8][8];
#pragma unroll
    for (int i = 0; i < 8; ++i)
#pragma unroll
        for (int j = 0; j < 8; ++j) acc[i][j] = 0u;
    const int sr = t >> 3;
    const int sc = (t << 1) & 15;
    for (int ks = 0; ks < K_DIM / (KT * 64); ++ks) {
        const int cbase = ks * KT;
#pragma unroll
        for (int i = 0; i < 4; ++i) {
            int r = i * 32 + sr;
            u64x2 va = *reinterpret_cast<const u64x2*>(A + (size_t)(m_blk + r) * KC + cbase + sc);
            As[sc][r] = va.x; As[sc + 1][r] = va.y;
            u64x2 vb = *reinterpret_cast<const u64x2*>(B + (size_t)(n_blk + r) * KC + cbase + sc);
            Bs[sc][r] = vb.x; Bs[sc + 1][r] = vb.y;
        }
        __syncthreads();
#pragma unroll 1
        for (int c = 0; c < KT; ++c) {
            u64 a[8], b[8];
#pragma unroll
            for (int i = 0; i < 4; ++i) {
                u64x2 va = *reinterpret_cast<const u64x2*>(&As[c][m0 + 2 * i]);
                a[2 * i] = va.x; a[2 * i + 1] = va.y;
                u64x2 vb = *reinterpret_cast<const u64x2*>(&Bs[c][n0 + 2 * i]);
                b[2 * i] = vb.x; b[2 * i + 1] = vb.y;
            }
#pragma unroll
            for (int i = 0; i < 8; ++i)
#pragma unroll
                for (int j = 0; j < 8; ++j)
                    acc[i][j] += (unsigned)__builtin_popcountll(a[i] ^ b[j]);
        }
        __syncthreads();
    }
#pragma unroll
    for (int i = 0; i < 8; ++i) {
        float* o = C + (size_t)(m_blk + m0 + i) * N_DIM + n_blk + n0;
        float4 v0, v1;
        v0.x = (float)(K_DIM - 2 * (int)acc[i][0]);
        v0.y = (float)(K_DIM - 2 * (int)acc[i][1]);
        v0.z = (float)(K_DIM - 2 * (int)acc[i][2]);
        v0.w = (float)(K_DIM - 2 * (int)acc[i][3]);
        v1.x = (float)(K_DIM - 2 * (int)acc[i][4]);
        v1.y = (float)(K_DIM - 2 * (int)acc[i][5]);
        v1.z = (float)(K_DIM - 2 * (int)acc[i][6]);
        v1.w = (float)(K_DIM - 2 * (int)acc[i][7]);
        *reinterpret_cast<float4*>(o)     = v0;
        *reinterpret_cast<float4*>(o + 4) = v1;
    }
}

extern "C" void kernel_launch(void* const* d_in, const int* in_sizes, int n_in,
                              void* d_out, int out_size, void* d_ws, size_t ws_size,
                              hipStream_t stream) {
    const float* x = (const float*)d_in[0];
    const float* w = (const float*)d_in[1];
    float* out = (float*)d_out;

    const size_t needA = (size_t)M_DIM * K_DIM / 2;      // 16 MiB packed fp4 A
    const size_t needB = (size_t)N_DIM * K_DIM / 2;      // 2 MiB packed fp4 B
    if (ws_size >= needA + needB) {
        char* Ap = (char*)d_ws;
        char* Bp = Ap + needA;
        // A: 64 m_blks x 16 stages x 2 subs x 8 t = 16384 waves / 4 per block
        pack_fp4_kernel<<<4096, 256, 0, stream>>>(x, Ap);
        // B: 8 n_blks -> 2048 waves
        pack_fp4_kernel<<<512, 256, 0, stream>>>(w, Bp);
        bgemm_fp4_kernel<<<(M_DIM / BM) * (N_DIM / BN), 512, 0, stream>>>(Ap, Bp, out);
    } else {
        u64* xb = (u64*)d_ws;
        u64* wb = xb + (size_t)M_DIM * KC;
        int xgroups = (M_DIM * K_DIM) / 256;
        int wgroups = (N_DIM * K_DIM) / 256;
        pack_sign_kernel<<<xgroups / 4, 256, 0, stream>>>(x, xb, xgroups);
        pack_sign_kernel<<<wgroups / 4, 256, 0, stream>>>(w, wb, wgroups);
        bgemm_kernel<<<dim3(N_DIM / 128, M_DIM / 128), 256, 0, stream>>>(xb, wb, out);
    }
}